// Round 4
// baseline (544.212 us; speedup 1.0000x reference)
//
#include <hip/hip_runtime.h>

// Masked attention B=8, NQ=1024, S=2048, D=512, fp32 in/out.
// prep: K -> Khi/Klo bf16 split + V -> Vt bf16 [b][d][s] (one kernel).
// attn: WG = 4 waves (256 thr), QT=16 q-rows, TS=64 s-tile, full S sweep.
//   Wave cw owns s-cols [cw*16,cw*16+16) for QK and d-slice [cw*128,+128) for PV.
//   K/V B-frags read directly from global (L2-hot); LDS only for P + stats
//   (~3 KB) -> 2 WGs/CU co-resident, barriers drain almost nothing.
//   QK = split-bf16 (hi*hi + lo*hi + hi*lo); PV bf16; online masked softmax
//   with per-slice stats + deferred rescale at P A-frag read.

#define Bz 8
#define NQz 1024
#define Sz 2048
#define Dz 512
#define QT 16
#define TS 64
#define NT (Sz / TS)
#define PP 72

typedef short bf16x8 __attribute__((ext_vector_type(8)));
typedef float f32x4 __attribute__((ext_vector_type(4)));
typedef unsigned short ushort_t;

__device__ __forceinline__ unsigned short f2bf(float x) {
  unsigned u = __builtin_bit_cast(unsigned, x);
  unsigned r = (u + 0x7FFFu + ((u >> 16) & 1u)) >> 16;  // RNE
  return (unsigned short)r;
}
__device__ __forceinline__ float bf2f(unsigned short h) {
  unsigned u = ((unsigned)h) << 16;
  return __builtin_bit_cast(float, u);
}

// ---------------- prep: K split + V transpose in one kernel ----------------
// blocks [0, 8192): K fp32 -> Khi,Klo bf16 (8192*256*4 = 8.39M elems)
// blocks [8192, 12288): V fp32 [b][s][d] -> Vt bf16 [b][d][s]
__global__ __launch_bounds__(256)
void prep(const float* __restrict__ K, const float* __restrict__ V,
          ushort_t* __restrict__ Khi, ushort_t* __restrict__ Klo,
          ushort_t* __restrict__ Vt) {
  __shared__ ushort_t sT[32][72];
  const int t = threadIdx.x;
  int bx = blockIdx.x;
  if (bx < 8192) {
    size_t e = ((size_t)bx * 256 + t) * 4;
    float4 v = *(const float4*)(K + e);
    float vv[4] = {v.x, v.y, v.z, v.w};
    unsigned short h[4], l[4];
#pragma unroll
    for (int j = 0; j < 4; ++j) {
      h[j] = f2bf(vv[j]);
      l[j] = f2bf(vv[j] - bf2f(h[j]));
    }
    uint2 hw, lw;
    hw.x = (unsigned)h[0] | ((unsigned)h[1] << 16);
    hw.y = (unsigned)h[2] | ((unsigned)h[3] << 16);
    lw.x = (unsigned)l[0] | ((unsigned)l[1] << 16);
    lw.y = (unsigned)l[2] | ((unsigned)l[3] << 16);
    *(uint2*)(Khi + e) = hw;
    *(uint2*)(Klo + e) = lw;
    return;
  }
  bx -= 8192;
  const int b = bx >> 9;
  const int rest = bx & 511;
  const int st = rest >> 3;
  const int dt = rest & 7;
  const int s0 = st * 32, d0 = dt * 64;
  const float* Vb = V + ((size_t)b * Sz + s0) * Dz + d0;
#pragma unroll
  for (int i = 0; i < 2; ++i) {
    int idx = t + 256 * i;
    int s = idx >> 4;
    int dc = (idx & 15) * 4;
    float4 v = *(const float4*)(Vb + (size_t)s * Dz + dc);
    uint2 w;
    w.x = (unsigned)f2bf(v.x) | ((unsigned)f2bf(v.y) << 16);
    w.y = (unsigned)f2bf(v.z) | ((unsigned)f2bf(v.w) << 16);
    *(uint2*)(&sT[s][dc]) = w;
  }
  __syncthreads();
  ushort_t* VtB = Vt + ((size_t)b * Dz + d0) * Sz + s0;
  {
    int d = t >> 2, c = t & 3;
    uint4 u;
    ushort_t* tp = (ushort_t*)&u;
#pragma unroll
    for (int j = 0; j < 8; ++j) tp[j] = sT[c * 8 + j][d];
    *(uint4*)(VtB + (size_t)d * Sz + c * 8) = u;
  }
}

// ---------------- attention ----------------
__global__ __launch_bounds__(256, 2)
void attn_flash(const float* __restrict__ Q, const int* __restrict__ Msk,
                const ushort_t* __restrict__ Khi, const ushort_t* __restrict__ Klo,
                const ushort_t* __restrict__ Vt, float* __restrict__ Out) {
  __shared__ ushort_t sP[QT][PP];
  __shared__ float sTMax[4][QT];
  __shared__ float sTSum[4][QT];
  __shared__ float sM[2][QT];
  __shared__ float sL[2][QT];

  const int tid  = threadIdx.x;
  const int cw   = tid >> 6;   // wave = s-col slice (QK) / d slice (PV)
  const int lane = tid & 63;
  const int l16  = lane & 15;
  const int quad = lane >> 4;

  // swizzle: blocks c and c+256 -> same XCD, same batch, adjacent q-tiles
  const int bx = blockIdx.x;
  const int j  = bx >> 8;
  const int c  = bx & 255;
  const int b  = c >> 5;
  const int qt = ((c & 31) << 1) | j;
  const int q0 = qt * QT;

  const float*    Qb  = Q   + ((size_t)b * NQz + q0) * Dz;
  const ushort_t* KhB = Khi + (size_t)b * Sz * Dz;
  const ushort_t* KlB = Klo + (size_t)b * Sz * Dz;
  const ushort_t* VtB = Vt  + (size_t)b * Dz * Sz;
  const int*      Mb  = Msk + ((size_t)b * NQz + q0) * (size_t)Sz;

  int msk_r[4];
#pragma unroll
  for (int r = 0; r < 4; ++r)
    msk_r[r] = Mb[(size_t)(quad * 4 + r) * Sz + cw * 16 + l16];

  // Q A-frags (rows l16), hi/lo bf16 split, register-resident for all K=512
  bf16x8 qhi[16], qlo[16];
  {
    const float* qrow = Qb + (size_t)l16 * Dz;
#pragma unroll
    for (int kk = 0; kk < 16; ++kk) {
      const float4 a = *(const float4*)(qrow + kk * 32 + quad * 8);
      const float4 d = *(const float4*)(qrow + kk * 32 + quad * 8 + 4);
      float v[8] = {a.x, a.y, a.z, a.w, d.x, d.y, d.z, d.w};
      bf16x8 h, l;
#pragma unroll
      for (int jj = 0; jj < 8; ++jj) {
        unsigned short hb = f2bf(v[jj]);
        h[jj] = (short)hb;
        l[jj] = (short)f2bf(v[jj] - bf2f(hb));
      }
      qhi[kk] = h;
      qlo[kk] = l;
    }
  }

  if (tid < QT) { sM[0][tid] = -1e30f; sL[0][tid] = 0.0f; }

  f32x4 oacc[8];
#pragma unroll
  for (int t = 0; t < 8; ++t) oacc[t] = (f32x4){0.f, 0.f, 0.f, 0.f};

  int p = 0;
  for (int i = 0; i < NT; ++i) {
    const int s0 = i * TS;

    __syncthreads();  // B1: phase-B(i-1) sP reads done before phase-A write

    // ---- QK^T: 16-col slice cw, 3-MFMA split, B-frags from global ----
    f32x4 sc = (f32x4){0.f, 0.f, 0.f, 0.f};
    {
      const ushort_t* kh = KhB + (size_t)(s0 + cw * 16 + l16) * Dz + quad * 8;
      const ushort_t* kl = KlB + (size_t)(s0 + cw * 16 + l16) * Dz + quad * 8;
#pragma unroll
      for (int kk = 0; kk < 16; ++kk) {
        bf16x8 bh = *(const bf16x8*)(kh + kk * 32);
        bf16x8 bl = *(const bf16x8*)(kl + kk * 32);
        sc = __builtin_amdgcn_mfma_f32_16x16x32_bf16(qhi[kk], bh, sc, 0, 0, 0);
        sc = __builtin_amdgcn_mfma_f32_16x16x32_bf16(qlo[kk], bh, sc, 0, 0, 0);
        sc = __builtin_amdgcn_mfma_f32_16x16x32_bf16(qhi[kk], bl, sc, 0, 0, 0);
      }
    }

    // ---- phase A: mask, per-slice max + expsum, write P' ----
    float se[4];
#pragma unroll
    for (int r = 0; r < 4; ++r) se[r] = msk_r[r] ? sc[r] : -1e30f;
    float rmax[4] = {se[0], se[1], se[2], se[3]};
#pragma unroll
    for (int d = 1; d < 16; d <<= 1) {
#pragma unroll
      for (int r = 0; r < 4; ++r) rmax[r] = fmaxf(rmax[r], __shfl_xor(rmax[r], d));
    }
    float rsum[4];
#pragma unroll
    for (int r = 0; r < 4; ++r) {
      int row = quad * 4 + r;
      float pv = msk_r[r] ? __expf(sc[r] - rmax[r]) : 0.0f;
      unsigned short pb = f2bf(pv);
      sP[row][cw * 16 + l16] = pb;
      rsum[r] = bf2f(pb);
    }
#pragma unroll
    for (int d = 1; d < 16; d <<= 1) {
#pragma unroll
      for (int r = 0; r < 4; ++r) rsum[r] += __shfl_xor(rsum[r], d);
    }
    if (l16 == 0) {
#pragma unroll
      for (int r = 0; r < 4; ++r) {
        int row = quad * 4 + r;
        sTMax[cw][row] = rmax[r];
        sTSum[cw][row] = rsum[r];
      }
    }

    __syncthreads();  // B3: P + stats visible

    // prefetch next tile's mask (consumed in next phase A)
    {
      const int sN = (i + 1 < NT) ? s0 + TS : 0;
#pragma unroll
      for (int r = 0; r < 4; ++r)
        msk_r[r] = Mb[(size_t)(quad * 4 + r) * Sz + sN + cw * 16 + l16];
    }

    // ---- phase B: merge stats, deferred-rescale P, PV from global ----
    {
      // per-lane stats for A-frag row l16
      float t0 = sTMax[0][l16], t1 = sTMax[1][l16];
      float t2 = sTMax[2][l16], t3 = sTMax[3][l16];
      float mo16 = sM[p][l16];
      float mn16 = fmaxf(fmaxf(fmaxf(t0, t1), fmaxf(t2, t3)), mo16);
      float e0 = __expf(t0 - mn16), e1 = __expf(t1 - mn16);
      float e2 = __expf(t2 - mn16), e3 = __expf(t3 - mn16);
      float scl0 = (quad >> 1) ? e1 : e0;   // kk=0 cols: slice quad>>1
      float scl1 = (quad >> 1) ? e3 : e2;   // kk=1 cols: slice 2+(quad>>1)
      bf16x8 praw0 = *(const bf16x8*)(&sP[l16][quad * 8]);
      bf16x8 praw1 = *(const bf16x8*)(&sP[l16][32 + quad * 8]);
      bf16x8 pa0, pa1;
#pragma unroll
      for (int jj = 0; jj < 8; ++jj) {
        pa0[jj] = (short)f2bf(bf2f((ushort_t)praw0[jj]) * scl0);
        pa1[jj] = (short)f2bf(bf2f((ushort_t)praw1[jj]) * scl1);
      }
      if (cw == 0 && quad == 0) {
        sM[p ^ 1][l16] = mn16;
        sL[p ^ 1][l16] = __expf(mo16 - mn16) * sL[p][l16] +
                         e0 * sTSum[0][l16] + e1 * sTSum[1][l16] +
                         e2 * sTSum[2][l16] + e3 * sTSum[3][l16];
      }
      // alpha for this lane's C rows (quad*4+r)
      float alpha[4];
#pragma unroll
      for (int r = 0; r < 4; ++r) {
        int rc = quad * 4 + r;
        float mo = sM[p][rc];
        float mn = fmaxf(fmaxf(fmaxf(sTMax[0][rc], sTMax[1][rc]),
                               fmaxf(sTMax[2][rc], sTMax[3][rc])), mo);
        alpha[r] = __expf(mo - mn);
      }
#pragma unroll
      for (int t = 0; t < 8; ++t) {
#pragma unroll
        for (int r = 0; r < 4; ++r) oacc[t][r] *= alpha[r];
      }
      const ushort_t* vb0 = VtB + (size_t)(cw * 128 + l16) * Sz + s0 + quad * 8;
#pragma unroll
      for (int t = 0; t < 8; ++t) {
        bf16x8 vb_a = *(const bf16x8*)(vb0 + (size_t)t * 16 * Sz);
        bf16x8 vb_b = *(const bf16x8*)(vb0 + (size_t)t * 16 * Sz + 32);
        oacc[t] = __builtin_amdgcn_mfma_f32_16x16x32_bf16(pa0, vb_a, oacc[t], 0, 0, 0);
        oacc[t] = __builtin_amdgcn_mfma_f32_16x16x32_bf16(pa1, vb_b, oacc[t], 0, 0, 0);
      }
    }
    p ^= 1;
  }

  __syncthreads();  // final sL (buffer p) visible
  float linv[4];
#pragma unroll
  for (int r = 0; r < 4; ++r) linv[r] = 1.0f / sL[p][quad * 4 + r];
#pragma unroll
  for (int t = 0; t < 8; ++t) {
#pragma unroll
    for (int r = 0; r < 4; ++r) {
      Out[((size_t)b * NQz + q0 + quad * 4 + r) * Dz + cw * 128 + t * 16 + l16] =
          oacc[t][r] * linv[r];
    }
  }
}

extern "C" void kernel_launch(void* const* d_in, const int* in_sizes, int n_in,
                              void* d_out, int out_size, void* d_ws, size_t ws_size,
                              hipStream_t stream) {
  const float* Q = (const float*)d_in[0];
  const float* K = (const float*)d_in[1];
  const float* V = (const float*)d_in[2];
  const int*   M = (const int*)d_in[3];
  float* O = (float*)d_out;

  const size_t NKV = (size_t)Bz * Sz * Dz;
  ushort_t* Khi = (ushort_t*)d_ws;
  ushort_t* Klo = Khi + NKV;
  ushort_t* Vt  = Klo + NKV;

  prep<<<dim3(12288), dim3(256), 0, stream>>>(K, V, Khi, Klo, Vt);
  attn_flash<<<dim3(512), dim3(256), 0, stream>>>(Q, M, Khi, Klo, Vt, O);
}

// Round 7
// 270.699 us; speedup vs baseline: 2.0104x; 2.0104x over previous
//
#include <hip/hip_runtime.h>

// Masked attention B=8, NQ=1024, S=2048, D=512, fp32 in/out.
// prep: K -> Kf fp16, V -> Vt fp16 [b][d][s] (one kernel).
// attn_flash: flash online masked softmax, all-fp16 MFMA (QK 1 MFMA/k-step,
//   PV fp16). LDS+DMA staging; 4-wave WGs with ~70 KB LDS so TWO independent
//   WGs co-reside per CU (independent barriers hide DMA drains).
//   QT=32 q-rows/WG, TS=32 s-tile, S-split=2 -> 512 WGs. 2 barriers/tile.
//   Schedule: V(i) issued post-B1(i), drained at B3(i), consumed phase B(i).
//   K(i+1) issued post-B3(i), drained at B1(i+1), consumed QK(i+1).
//   r6 lesson: __syncthreads() alone did not reliably drain the LDS-DMA
//   (first call passed, graph replay failed) -> every barrier that must
//   observe DMA data is now preceded by an EXPLICIT s_waitcnt(0).
// combine: merge the 2 S-halves.

#define Bz 8
#define NQz 1024
#define Sz 2048
#define Dz 512
#define QT 32
#define TS 32
#define NT ((Sz / 2) / TS)
#define KP 520   // sK row pitch (f16 elems); 1040B rows
#define PP 40

typedef _Float16 f16x8 __attribute__((ext_vector_type(8)));
typedef float f32x4 __attribute__((ext_vector_type(4)));
typedef unsigned short ushort_t;

#define AS1(p) ((const __attribute__((address_space(1))) unsigned int*)(p))
#define AS3(p) ((__attribute__((address_space(3))) unsigned int*)(p))
// wait vmcnt(0) expcnt(0) lgkmcnt(0) — explicit drain of LDS-DMA before barriers
#define DRAIN_ALL() __builtin_amdgcn_s_waitcnt(0)

__device__ __forceinline__ ushort_t f2h(float x) {
  _Float16 h = (_Float16)x;  // RNE
  return __builtin_bit_cast(ushort_t, h);
}
__device__ __forceinline__ float h2f(ushort_t u) {
  return (float)__builtin_bit_cast(_Float16, u);
}

// ---------------- prep: K -> fp16, V -> Vt fp16 transposed ----------------
// blocks [0, 8192): K fp32 -> Kf fp16 (1024 elems/block)
// blocks [8192, 12288): V fp32 [b][s][d] -> Vt fp16 [b][d][s] (32x64 tiles)
__global__ __launch_bounds__(256)
void prep(const float* __restrict__ K, const float* __restrict__ V,
          ushort_t* __restrict__ Kf, ushort_t* __restrict__ Vt) {
  __shared__ ushort_t sT[32][72];
  const int t = threadIdx.x;
  int bx = blockIdx.x;
  if (bx < 8192) {
    size_t e = ((size_t)bx * 256 + t) * 4;
    float4 v = *(const float4*)(K + e);
    uint2 w;
    w.x = (unsigned)f2h(v.x) | ((unsigned)f2h(v.y) << 16);
    w.y = (unsigned)f2h(v.z) | ((unsigned)f2h(v.w) << 16);
    *(uint2*)(Kf + e) = w;
    return;
  }
  bx -= 8192;
  const int b = bx >> 9;
  const int rest = bx & 511;
  const int st = rest >> 3;
  const int dt = rest & 7;
  const int s0 = st * 32, d0 = dt * 64;
  const float* Vb = V + ((size_t)b * Sz + s0) * Dz + d0;
#pragma unroll
  for (int i = 0; i < 2; ++i) {
    int idx = t + 256 * i;
    int s = idx >> 4;
    int dc = (idx & 15) * 4;
    float4 v = *(const float4*)(Vb + (size_t)s * Dz + dc);
    uint2 w;
    w.x = (unsigned)f2h(v.x) | ((unsigned)f2h(v.y) << 16);
    w.y = (unsigned)f2h(v.z) | ((unsigned)f2h(v.w) << 16);
    *(uint2*)(&sT[s][dc]) = w;
  }
  __syncthreads();
  ushort_t* VtB = Vt + ((size_t)b * Dz + d0) * Sz + s0;
  {
    int d = t >> 2, c = t & 3;
    uint4 u;
    ushort_t* tp = (ushort_t*)&u;
#pragma unroll
    for (int j = 0; j < 8; ++j) tp[j] = sT[c * 8 + j][d];
    *(uint4*)(VtB + (size_t)d * Sz + c * 8) = u;
  }
}

// ---------------- attention ----------------
__global__ __launch_bounds__(256, 2)
void attn_flash(const float* __restrict__ Q, const int* __restrict__ Msk,
                const ushort_t* __restrict__ Kf, const ushort_t* __restrict__ Vt,
                float* __restrict__ Opart, float* __restrict__ Mpart,
                float* __restrict__ Lpart) {
  __shared__ ushort_t sK[TS][KP];       // 33.3 KB
  __shared__ ushort_t sV[Dz][TS];       // 32.8 KB, pitch 64B (DMA-contiguous)
  __shared__ ushort_t sP[QT][PP];       // 2.6 KB
  __shared__ float sTMax[2][QT];
  __shared__ float sTSum[2][QT];
  __shared__ float sM[2][QT];
  __shared__ float sL[2][QT];

  const int tid  = threadIdx.x;
  const int wave = tid >> 6;
  const int lane = tid & 63;
  const int l16  = lane & 15;
  const int quad = lane >> 4;
  const int rw   = wave & 1;   // q row-tile of 16
  const int cw   = wave >> 1;  // s col-half (QK) / d half (PV)

  const int bx = blockIdx.x;
  const int b  = bx >> 6;
  const int r6 = bx & 63;
  const int qt = r6 >> 1;
  const int sh = r6 & 1;
  const int q0 = qt * QT;
  const int sbeg = sh * (Sz / 2);

  const float*    Qb  = Q  + ((size_t)b * NQz + q0) * Dz;
  const ushort_t* KfB = Kf + (size_t)b * Sz * Dz;
  const ushort_t* VtB = Vt + (size_t)b * Dz * Sz;
  const int*      Mb  = Msk + ((size_t)b * NQz + q0) * (size_t)Sz;

  int msk_r[4];

  auto issue_k = [&](int s0n) {
#pragma unroll
    for (int j = 0; j < 8; ++j) {
      int row = wave * 8 + j;
      const ushort_t* gp = KfB + (size_t)(s0n + row) * Dz + lane * 8;
      __builtin_amdgcn_global_load_lds(AS1(gp), AS3(&sK[row][0]), 16, 0, 0);
    }
  };
  auto issue_v = [&](int s0n) {
#pragma unroll
    for (int j = 0; j < 8; ++j) {
      int dbase = wave * 128 + j * 16;
      const ushort_t* gp =
          VtB + (size_t)(dbase + (lane >> 2)) * Sz + s0n + (lane & 3) * 8;
      __builtin_amdgcn_global_load_lds(AS1(gp), AS3(&sV[dbase][0]), 16, 0, 0);
    }
  };
  auto load_mask = [&](int s0n) {
#pragma unroll
    for (int r = 0; r < 4; ++r) {
      int qrow = rw * 16 + quad * 4 + r;
      msk_r[r] = Mb[(size_t)qrow * Sz + s0n + cw * 16 + l16];
    }
  };

  // prologue: K(0) + mask(0) in flight before the heavy Q load
  issue_k(sbeg);
  load_mask(sbeg);

  // Q A-frags fp16 (rows rw*16+l16), register-resident for all K=512
  f16x8 qa[16];
  {
    const float* qrow = Qb + (size_t)(rw * 16 + l16) * Dz;
#pragma unroll
    for (int kk = 0; kk < 16; ++kk) {
      const float4 a = *(const float4*)(qrow + kk * 32 + quad * 8);
      const float4 c = *(const float4*)(qrow + kk * 32 + quad * 8 + 4);
      f16x8 h;
      h[0] = (_Float16)a.x; h[1] = (_Float16)a.y;
      h[2] = (_Float16)a.z; h[3] = (_Float16)a.w;
      h[4] = (_Float16)c.x; h[5] = (_Float16)c.y;
      h[6] = (_Float16)c.z; h[7] = (_Float16)c.w;
      qa[kk] = h;
    }
  }

  if (tid < QT) { sM[0][tid] = -1e30f; sL[0][tid] = 0.0f; }

  f32x4 oacc[16];
#pragma unroll
  for (int t = 0; t < 16; ++t) oacc[t] = (f32x4){0.f, 0.f, 0.f, 0.f};

  int p = 0;
  for (int i = 0; i < NT; ++i) {
    const int s0 = sbeg + i * TS;
    const int sNext = (i + 1 < NT) ? s0 + TS : sbeg;  // wraps; junk unread

    DRAIN_ALL();      // explicit: K(i) DMA retired before anyone crosses B1
    __syncthreads();  // B1: phase-B(i-1) sV/sP reads done

    issue_v(s0);  // V(i): overlaps QK+phaseA, drained at B3(i), read phase B(i)

    // ---- QK^T: tile (rw, cw), 1 MFMA per k-step, fp16 ----
    f32x4 sc = (f32x4){0.f, 0.f, 0.f, 0.f};
    {
      const ushort_t* kh = &sK[cw * 16 + l16][quad * 8];
#pragma unroll
      for (int kk = 0; kk < 16; ++kk) {
        f16x8 bh = *(const f16x8*)(kh + kk * 32);
        sc = __builtin_amdgcn_mfma_f32_16x16x32_f16(qa[kk], bh, sc, 0, 0, 0);
      }
    }

    // ---- phase A: mask, per-half max + expsum, write P' (fp16) ----
    float se[4];
#pragma unroll
    for (int r = 0; r < 4; ++r) se[r] = msk_r[r] ? sc[r] : -1e30f;
    float rmax[4] = {se[0], se[1], se[2], se[3]};
#pragma unroll
    for (int d = 1; d < 16; d <<= 1) {
#pragma unroll
      for (int r = 0; r < 4; ++r) rmax[r] = fmaxf(rmax[r], __shfl_xor(rmax[r], d));
    }
    float rsum[4];
#pragma unroll
    for (int r = 0; r < 4; ++r) {
      int row = rw * 16 + quad * 4 + r;
      float pv = msk_r[r] ? __expf(sc[r] - rmax[r]) : 0.0f;
      ushort_t pb = f2h(pv);
      sP[row][cw * 16 + l16] = pb;
      rsum[r] = h2f(pb);
    }
#pragma unroll
    for (int d = 1; d < 16; d <<= 1) {
#pragma unroll
      for (int r = 0; r < 4; ++r) rsum[r] += __shfl_xor(rsum[r], d);
    }
    if (l16 == 0) {
#pragma unroll
      for (int r = 0; r < 4; ++r) {
        int row = rw * 16 + quad * 4 + r;
        sTMax[cw][row] = rmax[r];
        sTSum[cw][row] = rsum[r];
      }
    }

    DRAIN_ALL();      // explicit: V(i) DMA retired before anyone crosses B3
    __syncthreads();  // B3: P + stats visible

    issue_k(sNext);    // K(i+1): sK reads done in QK(i); drained at B1(i+1)
    load_mask(sNext);  // consumed next phase A

    // ---- phase B: merge stats, deferred-rescale P A-frag, PV (fp16) ----
    const int pr = p;
    {
      const int row16 = rw * 16 + l16;
      float t0v = sTMax[0][row16], t1v = sTMax[1][row16];
      float mo16 = sM[pr][row16];
      float mn16 = fmaxf(mo16, fmaxf(t0v, t1v));
      float scl = __expf(((quad >> 1) ? t1v : t0v) - mn16);
      f16x8 praw = *(const f16x8*)(&sP[row16][quad * 8]);
      f16x8 pa;
#pragma unroll
      for (int j = 0; j < 8; ++j) pa[j] = (_Float16)((float)praw[j] * scl);

      float alpha[4];
#pragma unroll
      for (int r = 0; r < 4; ++r) {
        int rc = rw * 16 + quad * 4 + r;
        float a0 = sTMax[0][rc], a1 = sTMax[1][rc];
        float mo = sM[pr][rc];
        float mn = fmaxf(mo, fmaxf(a0, a1));
        float al = __expf(mo - mn);
        alpha[r] = al;
        if (cw == 0 && l16 == 0) {
          sM[pr ^ 1][rc] = mn;
          sL[pr ^ 1][rc] = al * sL[pr][rc] + __expf(a0 - mn) * sTSum[0][rc]
                                           + __expf(a1 - mn) * sTSum[1][rc];
        }
      }
#pragma unroll
      for (int t = 0; t < 16; ++t) {
#pragma unroll
        for (int r = 0; r < 4; ++r) oacc[t][r] *= alpha[r];
      }
#pragma unroll
      for (int t = 0; t < 16; ++t) {
        f16x8 vb = *(const f16x8*)(&sV[cw * 256 + t * 16 + l16][quad * 8]);
        oacc[t] = __builtin_amdgcn_mfma_f32_16x16x32_f16(pa, vb, oacc[t], 0, 0, 0);
      }
    }
    p ^= 1;
  }

  DRAIN_ALL();      // retire the wasted tail K-DMA before the final barrier
  __syncthreads();  // final sM/sL (buffer p) visible
  const size_t rbase = (size_t)(b * 2 + sh) * NQz + q0;
#pragma unroll
  for (int t = 0; t < 16; ++t) {
#pragma unroll
    for (int r = 0; r < 4; ++r) {
      int rowq = rw * 16 + quad * 4 + r;
      Opart[(rbase + rowq) * Dz + cw * 256 + t * 16 + l16] = oacc[t][r];
    }
  }
  if (tid < QT) {
    Mpart[rbase + tid] = sM[p][tid];
    Lpart[rbase + tid] = sL[p][tid];
  }
}

// ---------------- combine the two S-halves ----------------
__global__ __launch_bounds__(256)
void combine(const float* __restrict__ Opart, const float* __restrict__ Mpart,
             const float* __restrict__ Lpart, float* __restrict__ Out) {
  int gid = blockIdx.x * 256 + threadIdx.x;
  int row = gid >> 7;
  int b   = row >> 10;
  int q   = row & 1023;
  int c   = (gid & 127) * 4;
  size_t i0 = (size_t)(b * 2 + 0) * NQz + q;
  size_t i1 = (size_t)(b * 2 + 1) * NQz + q;
  float m0 = Mpart[i0], m1 = Mpart[i1];
  float l0 = Lpart[i0], l1 = Lpart[i1];
  float m  = fmaxf(m0, m1);
  float w0 = __expf(m0 - m), w1 = __expf(m1 - m);
  float inv = 1.0f / (w0 * l0 + w1 * l1);
  float4 a = *(const float4*)(Opart + i0 * Dz + c);
  float4 bv = *(const float4*)(Opart + i1 * Dz + c);
  float4 o;
  o.x = (w0 * a.x + w1 * bv.x) * inv;
  o.y = (w0 * a.y + w1 * bv.y) * inv;
  o.z = (w0 * a.z + w1 * bv.z) * inv;
  o.w = (w0 * a.w + w1 * bv.w) * inv;
  *(float4*)(Out + ((size_t)b * NQz + q) * Dz + c) = o;
}

extern "C" void kernel_launch(void* const* d_in, const int* in_sizes, int n_in,
                              void* d_out, int out_size, void* d_ws, size_t ws_size,
                              hipStream_t stream) {
  const float* Q = (const float*)d_in[0];
  const float* K = (const float*)d_in[1];
  const float* V = (const float*)d_in[2];
  const int*   M = (const int*)d_in[3];
  float* O = (float*)d_out;

  const size_t NKV = (size_t)Bz * Sz * Dz;
  ushort_t* Kf = (ushort_t*)d_ws;
  ushort_t* Vt = Kf + NKV;
  float* Opart = (float*)(Vt + NKV);
  float* Mpart = Opart + (size_t)Bz * 2 * NQz * Dz;
  float* Lpart = Mpart + (size_t)Bz * 2 * NQz;

  prep<<<dim3(12288), dim3(256), 0, stream>>>(K, V, Kf, Vt);
  attn_flash<<<dim3(512), dim3(256), 0, stream>>>(Q, M, Kf, Vt, Opart, Mpart, Lpart);
  combine<<<dim3(4096), dim3(256), 0, stream>>>(Opart, Mpart, Lpart, O);
}

// Round 8
// 257.170 us; speedup vs baseline: 2.1162x; 1.0526x over previous
//
#include <hip/hip_runtime.h>

// Masked attention B=8, NQ=1024, S=2048, D=512, fp32 in/out.
// prep: K -> Kf fp16, V -> Vt fp16 [b][d][s] (one kernel).
// attn_flash: flash online masked softmax, all-fp16 MFMA.
//   r8: OPERAND-SWAPPED QK (S^T = K·Q^T, same frags, args swapped) so the
//   score C-layout has lane=q, regs=s -> softmax reduction = 3 in-reg ops +
//   2 shuffles (was 32 serial shuffle ops); mask = one int4; P store = one
//   ds_write_b64. Dual QK accumulators halve the serial MFMA chain.
//   LDS+DMA staging; 4-wave WGs, ~70 KB LDS -> 2 independent WGs/CU.
//   QT=32, TS=32, S-split=2 -> 512 WGs. 2 barriers/tile.
//   V(i) issued post-B1(i) (drained at B3(i)); K(i+1) post-B3(i) (drained
//   at B1(i+1)). EXPLICIT s_waitcnt(0) before each draining barrier —
//   __syncthreads alone demonstrably does not retire the LDS-DMA (r6 bug).
// combine: merge the 2 S-halves.

#define Bz 8
#define NQz 1024
#define Sz 2048
#define Dz 512
#define QT 32
#define TS 32
#define NT ((Sz / 2) / TS)
#define KP 520   // sK row pitch (f16 elems); 1040B rows
#define PP 40

typedef _Float16 f16x8 __attribute__((ext_vector_type(8)));
typedef float f32x4 __attribute__((ext_vector_type(4)));
typedef unsigned short ushort_t;

#define AS1(p) ((const __attribute__((address_space(1))) unsigned int*)(p))
#define AS3(p) ((__attribute__((address_space(3))) unsigned int*)(p))
#define DRAIN_ALL() __builtin_amdgcn_s_waitcnt(0)

__device__ __forceinline__ ushort_t f2h(float x) {
  _Float16 h = (_Float16)x;  // RNE
  return __builtin_bit_cast(ushort_t, h);
}
__device__ __forceinline__ float h2f(ushort_t u) {
  return (float)__builtin_bit_cast(_Float16, u);
}

// ---------------- prep: K -> fp16, V -> Vt fp16 transposed ----------------
__global__ __launch_bounds__(256)
void prep(const float* __restrict__ K, const float* __restrict__ V,
          ushort_t* __restrict__ Kf, ushort_t* __restrict__ Vt) {
  __shared__ ushort_t sT[32][72];
  const int t = threadIdx.x;
  int bx = blockIdx.x;
  if (bx < 8192) {
    size_t e = ((size_t)bx * 256 + t) * 4;
    float4 v = *(const float4*)(K + e);
    uint2 w;
    w.x = (unsigned)f2h(v.x) | ((unsigned)f2h(v.y) << 16);
    w.y = (unsigned)f2h(v.z) | ((unsigned)f2h(v.w) << 16);
    *(uint2*)(Kf + e) = w;
    return;
  }
  bx -= 8192;
  const int b = bx >> 9;
  const int rest = bx & 511;
  const int st = rest >> 3;
  const int dt = rest & 7;
  const int s0 = st * 32, d0 = dt * 64;
  const float* Vb = V + ((size_t)b * Sz + s0) * Dz + d0;
#pragma unroll
  for (int i = 0; i < 2; ++i) {
    int idx = t + 256 * i;
    int s = idx >> 4;
    int dc = (idx & 15) * 4;
    float4 v = *(const float4*)(Vb + (size_t)s * Dz + dc);
    uint2 w;
    w.x = (unsigned)f2h(v.x) | ((unsigned)f2h(v.y) << 16);
    w.y = (unsigned)f2h(v.z) | ((unsigned)f2h(v.w) << 16);
    *(uint2*)(&sT[s][dc]) = w;
  }
  __syncthreads();
  ushort_t* VtB = Vt + ((size_t)b * Dz + d0) * Sz + s0;
  {
    int d = t >> 2, c = t & 3;
    uint4 u;
    ushort_t* tp = (ushort_t*)&u;
#pragma unroll
    for (int j = 0; j < 8; ++j) tp[j] = sT[c * 8 + j][d];
    *(uint4*)(VtB + (size_t)d * Sz + c * 8) = u;
  }
}

// ---------------- attention ----------------
__global__ __launch_bounds__(256, 2)
void attn_flash(const float* __restrict__ Q, const int* __restrict__ Msk,
                const ushort_t* __restrict__ Kf, const ushort_t* __restrict__ Vt,
                float* __restrict__ Opart, float* __restrict__ Mpart,
                float* __restrict__ Lpart) {
  __shared__ ushort_t sK[TS][KP];       // 33.3 KB
  __shared__ ushort_t sV[Dz][TS];       // 32.8 KB (64B rows, DMA-contiguous)
  __shared__ ushort_t sP[QT][PP];       // 2.6 KB
  __shared__ float sTMax[2][QT];
  __shared__ float sTSum[2][QT];
  __shared__ float sM[2][QT];
  __shared__ float sL[2][QT];

  const int tid  = threadIdx.x;
  const int wave = tid >> 6;
  const int lane = tid & 63;
  const int l16  = lane & 15;
  const int quad = lane >> 4;
  const int rw   = wave & 1;   // q row-tile of 16
  const int cw   = wave >> 1;  // s col-half (QK) / d half (PV)

  const int bx = blockIdx.x;
  const int b  = bx >> 6;
  const int r6 = bx & 63;
  const int qt = r6 >> 1;
  const int sh = r6 & 1;
  const int q0 = qt * QT;
  const int sbeg = sh * (Sz / 2);

  const float*    Qb  = Q  + ((size_t)b * NQz + q0) * Dz;
  const ushort_t* KfB = Kf + (size_t)b * Sz * Dz;
  const ushort_t* VtB = Vt + (size_t)b * Dz * Sz;
  const int*      Mb  = Msk + ((size_t)b * NQz + q0) * (size_t)Sz;

  int msk_r[4];

  auto issue_k = [&](int s0n) {
#pragma unroll
    for (int j = 0; j < 8; ++j) {
      int row = wave * 8 + j;
      const ushort_t* gp = KfB + (size_t)(s0n + row) * Dz + lane * 8;
      __builtin_amdgcn_global_load_lds(AS1(gp), AS3(&sK[row][0]), 16, 0, 0);
    }
  };
  auto issue_v = [&](int s0n) {
#pragma unroll
    for (int j = 0; j < 8; ++j) {
      int dbase = wave * 128 + j * 16;
      const ushort_t* gp =
          VtB + (size_t)(dbase + (lane >> 2)) * Sz + s0n + (lane & 3) * 8;
      __builtin_amdgcn_global_load_lds(AS1(gp), AS3(&sV[dbase][0]), 16, 0, 0);
    }
  };
  // S^T layout: lane l16 = q (within rw tile), quad*4+r = s (within cw half)
  auto load_mask = [&](int s0n) {
    const int4 mv = *(const int4*)(Mb + (size_t)(rw * 16 + l16) * Sz + s0n +
                                   cw * 16 + quad * 4);
    msk_r[0] = mv.x; msk_r[1] = mv.y; msk_r[2] = mv.z; msk_r[3] = mv.w;
  };

  // prologue: K(0) + mask(0) in flight before the heavy Q load
  issue_k(sbeg);
  load_mask(sbeg);

  // Q frags fp16 (rows rw*16+l16), register-resident; used as the B operand
  // of the swapped QK MFMA (B[k][n] lane mapping == A[m][k] lane mapping).
  f16x8 qa[16];
  {
    const float* qrow = Qb + (size_t)(rw * 16 + l16) * Dz;
#pragma unroll
    for (int kk = 0; kk < 16; ++kk) {
      const float4 a = *(const float4*)(qrow + kk * 32 + quad * 8);
      const float4 c = *(const float4*)(qrow + kk * 32 + quad * 8 + 4);
      f16x8 h;
      h[0] = (_Float16)a.x; h[1] = (_Float16)a.y;
      h[2] = (_Float16)a.z; h[3] = (_Float16)a.w;
      h[4] = (_Float16)c.x; h[5] = (_Float16)c.y;
      h[6] = (_Float16)c.z; h[7] = (_Float16)c.w;
      qa[kk] = h;
    }
  }

  if (tid < QT) { sM[0][tid] = -1e30f; sL[0][tid] = 0.0f; }

  f32x4 oacc[16];
#pragma unroll
  for (int t = 0; t < 16; ++t) oacc[t] = (f32x4){0.f, 0.f, 0.f, 0.f};

  int p = 0;
  for (int i = 0; i < NT; ++i) {
    const int s0 = sbeg + i * TS;
    const int sNext = (i + 1 < NT) ? s0 + TS : sbeg;  // wraps; junk unread

    DRAIN_ALL();      // K(i) DMA retired before anyone crosses B1
    __syncthreads();  // B1: phase-B(i-1) sV/sP reads done

    issue_v(s0);  // V(i): overlaps QK+phaseA, drained at B3(i), read phase B(i)

    // ---- S^T = K·Q^T: dual accumulators halve the serial MFMA chain ----
    // D[s][q]: col=lane=q (matches Q frag lane), row=quad*4+r = s.
    f32x4 sc0 = (f32x4){0.f, 0.f, 0.f, 0.f};
    f32x4 sc1 = (f32x4){0.f, 0.f, 0.f, 0.f};
    {
      const ushort_t* kh = &sK[cw * 16 + l16][quad * 8];
#pragma unroll
      for (int kk = 0; kk < 16; kk += 2) {
        f16x8 b0 = *(const f16x8*)(kh + kk * 32);
        f16x8 b1 = *(const f16x8*)(kh + kk * 32 + 32);
        sc0 = __builtin_amdgcn_mfma_f32_16x16x32_f16(b0, qa[kk], sc0, 0, 0, 0);
        sc1 = __builtin_amdgcn_mfma_f32_16x16x32_f16(b1, qa[kk + 1], sc1, 0, 0, 0);
      }
    }
    f32x4 sc;
#pragma unroll
    for (int r = 0; r < 4; ++r) sc[r] = sc0[r] + sc1[r];

    // ---- phase A: mask, per-half max + expsum (over s: 3 in-reg + 2 shfl) ----
    float se[4];
#pragma unroll
    for (int r = 0; r < 4; ++r) se[r] = msk_r[r] ? sc[r] : -1e30f;
    float rmax = fmaxf(fmaxf(se[0], se[1]), fmaxf(se[2], se[3]));
    rmax = fmaxf(rmax, __shfl_xor(rmax, 16));
    rmax = fmaxf(rmax, __shfl_xor(rmax, 32));
    // P' = exp(s - rmax) for this q (lane l16), s = cw*16 + quad*4 + r
    ushort_t pb[4];
    float rsum = 0.f;
#pragma unroll
    for (int r = 0; r < 4; ++r) {
      float pv = msk_r[r] ? __expf(se[r] - rmax) : 0.0f;
      pb[r] = f2h(pv);
      rsum += h2f(pb[r]);
    }
    {  // one ds_write_b64: sP[q][cw*16+quad*4 .. +4)
      uint2 w;
      w.x = (unsigned)pb[0] | ((unsigned)pb[1] << 16);
      w.y = (unsigned)pb[2] | ((unsigned)pb[3] << 16);
      *(uint2*)(&sP[rw * 16 + l16][cw * 16 + quad * 4]) = w;
    }
    rsum += __shfl_xor(rsum, 16);
    rsum += __shfl_xor(rsum, 32);
    if (quad == 0) {
      sTMax[cw][rw * 16 + l16] = rmax;
      sTSum[cw][rw * 16 + l16] = rsum;
    }

    DRAIN_ALL();      // V(i) DMA retired before anyone crosses B3
    __syncthreads();  // B3: P + stats visible

    issue_k(sNext);    // K(i+1): sK reads done in QK(i); drained at B1(i+1)
    load_mask(sNext);  // consumed next phase A

    // ---- phase B: merge stats, deferred-rescale P A-frag, PV (fp16) ----
    const int pr = p;
    {
      const int row16 = rw * 16 + l16;
      float t0v = sTMax[0][row16], t1v = sTMax[1][row16];
      float mo16 = sM[pr][row16];
      float mn16 = fmaxf(mo16, fmaxf(t0v, t1v));
      float scl = __expf(((quad >> 1) ? t1v : t0v) - mn16);
      f16x8 praw = *(const f16x8*)(&sP[row16][quad * 8]);
      f16x8 pa;
#pragma unroll
      for (int j = 0; j < 8; ++j) pa[j] = (_Float16)((float)praw[j] * scl);

      float alpha[4];
#pragma unroll
      for (int r = 0; r < 4; ++r) {
        int rc = rw * 16 + quad * 4 + r;
        float a0 = sTMax[0][rc], a1 = sTMax[1][rc];
        float mo = sM[pr][rc];
        float mn = fmaxf(mo, fmaxf(a0, a1));
        float al = __expf(mo - mn);
        alpha[r] = al;
        if (cw == 0 && l16 == 0) {
          sM[pr ^ 1][rc] = mn;
          sL[pr ^ 1][rc] = al * sL[pr][rc] + __expf(a0 - mn) * sTSum[0][rc]
                                           + __expf(a1 - mn) * sTSum[1][rc];
        }
      }
#pragma unroll
      for (int t = 0; t < 16; ++t) {
#pragma unroll
        for (int r = 0; r < 4; ++r) oacc[t][r] *= alpha[r];
      }
#pragma unroll
      for (int t = 0; t < 16; ++t) {
        f16x8 vb = *(const f16x8*)(&sV[cw * 256 + t * 16 + l16][quad * 8]);
        oacc[t] = __builtin_amdgcn_mfma_f32_16x16x32_f16(pa, vb, oacc[t], 0, 0, 0);
      }
    }
    p ^= 1;
  }

  DRAIN_ALL();      // retire the wasted tail K-DMA before the final barrier
  __syncthreads();  // final sM/sL (buffer p) visible
  const size_t rbase = (size_t)(b * 2 + sh) * NQz + q0;
#pragma unroll
  for (int t = 0; t < 16; ++t) {
#pragma unroll
    for (int r = 0; r < 4; ++r) {
      int rowq = rw * 16 + quad * 4 + r;
      Opart[(rbase + rowq) * Dz + cw * 256 + t * 16 + l16] = oacc[t][r];
    }
  }
  if (tid < QT) {
    Mpart[rbase + tid] = sM[p][tid];
    Lpart[rbase + tid] = sL[p][tid];
  }
}

// ---------------- combine the two S-halves ----------------
__global__ __launch_bounds__(256)
void combine(const float* __restrict__ Opart, const float* __restrict__ Mpart,
             const float* __restrict__ Lpart, float* __restrict__ Out) {
  int gid = blockIdx.x * 256 + threadIdx.x;
  int row = gid >> 7;
  int b   = row >> 10;
  int q   = row & 1023;
  int c   = (gid & 127) * 4;
  size_t i0 = (size_t)(b * 2 + 0) * NQz + q;
  size_t i1 = (size_t)(b * 2 + 1) * NQz + q;
  float m0 = Mpart[i0], m1 = Mpart[i1];
  float l0 = Lpart[i0], l1 = Lpart[i1];
  float m  = fmaxf(m0, m1);
  float w0 = __expf(m0 - m), w1 = __expf(m1 - m);
  float inv = 1.0f / (w0 * l0 + w1 * l1);
  float4 a = *(const float4*)(Opart + i0 * Dz + c);
  float4 bv = *(const float4*)(Opart + i1 * Dz + c);
  float4 o;
  o.x = (w0 * a.x + w1 * bv.x) * inv;
  o.y = (w0 * a.y + w1 * bv.y) * inv;
  o.z = (w0 * a.z + w1 * bv.z) * inv;
  o.w = (w0 * a.w + w1 * bv.w) * inv;
  *(float4*)(Out + ((size_t)b * NQz + q) * Dz + c) = o;
}

extern "C" void kernel_launch(void* const* d_in, const int* in_sizes, int n_in,
                              void* d_out, int out_size, void* d_ws, size_t ws_size,
                              hipStream_t stream) {
  const float* Q = (const float*)d_in[0];
  const float* K = (const float*)d_in[1];
  const float* V = (const float*)d_in[2];
  const int*   M = (const int*)d_in[3];
  float* O = (float*)d_out;

  const size_t NKV = (size_t)Bz * Sz * Dz;
  ushort_t* Kf = (ushort_t*)d_ws;
  ushort_t* Vt = Kf + NKV;
  float* Opart = (float*)(Vt + NKV);
  float* Mpart = Opart + (size_t)Bz * 2 * NQz * Dz;
  float* Lpart = Mpart + (size_t)Bz * 2 * NQz;

  prep<<<dim3(12288), dim3(256), 0, stream>>>(K, V, Kf, Vt);
  attn_flash<<<dim3(512), dim3(256), 0, stream>>>(Q, M, Kf, Vt, Opart, Mpart, Lpart);
  combine<<<dim3(4096), dim3(256), 0, stream>>>(Opart, Mpart, Lpart, O);
}